// Round 2
// baseline (751.797 us; speedup 1.0000x reference)
//
#include <hip/hip_runtime.h>
#include <hip/hip_bf16.h>
#include <cstdint>

#define NN   50000
#define EE   800000
#define DIN_ 256
#define HD_  256     // H*DH
#define DH_  64
#define NH_  4
#define NC_  10
#define NG_  100
#define EPS_ 1e-4f
#define SLOPE_ 0.01f

__device__ __forceinline__ float leaky(float x) { return x >= 0.f ? x : SLOPE_ * x; }
__device__ __forceinline__ float sigm(float x)  { return 1.f / (1.f + __expf(-x)); }

// ---------------- init: zero deg/cursor/gsum/gcnt ----------------
__global__ void init_zero(int* deg, int* cursor, float* gsum, float* gcnt) {
    int i = blockIdx.x * 256 + threadIdx.x;
    if (i < NN) { deg[i] = 0; cursor[i] = 0; }
    if (i < NG_ * NC_) gsum[i] = 0.f;
    if (i < NG_) gcnt[i] = 0.f;
}

// ---------------- GEMM: h = x @ W_feat  (fp32) ----------------
// BM=64 BN=64 BK=32, 256 threads, 4x4 per thread
__global__ __launch_bounds__(256) void gemm_h(const float* __restrict__ x,
                                              const float* __restrict__ w,
                                              float* __restrict__ hfeat) {
    __shared__ float As[32][68];  // [k][m], +4 pad
    __shared__ float Bs[32][68];  // [k][n]
    const int tid = threadIdx.x;
    const int row0 = blockIdx.x * 64;
    const int col0 = blockIdx.y * 64;
    const int tx = tid & 15, ty = tid >> 4;
    const int lr = tid >> 2, lk = (tid & 3) * 8;   // x loader: row lr, 8 k's
    const int wk = tid >> 3, wn = (tid & 7) * 8;   // w loader: k row wk, 8 n's

    float acc[4][4] = {};

    for (int k0 = 0; k0 < DIN_; k0 += 32) {
        float4 x0 = make_float4(0.f, 0.f, 0.f, 0.f), x1 = x0;
        int grow = row0 + lr;
        if (grow < NN) {
            const float4* xp = (const float4*)(x + (size_t)grow * DIN_ + k0 + lk);
            x0 = xp[0]; x1 = xp[1];
        }
        As[lk + 0][lr] = x0.x; As[lk + 1][lr] = x0.y;
        As[lk + 2][lr] = x0.z; As[lk + 3][lr] = x0.w;
        As[lk + 4][lr] = x1.x; As[lk + 5][lr] = x1.y;
        As[lk + 6][lr] = x1.z; As[lk + 7][lr] = x1.w;
        const float4* wp = (const float4*)(w + (size_t)(k0 + wk) * HD_ + col0 + wn);
        float4 w0 = wp[0], w1 = wp[1];
        Bs[wk][wn + 0] = w0.x; Bs[wk][wn + 1] = w0.y;
        Bs[wk][wn + 2] = w0.z; Bs[wk][wn + 3] = w0.w;
        Bs[wk][wn + 4] = w1.x; Bs[wk][wn + 5] = w1.y;
        Bs[wk][wn + 6] = w1.z; Bs[wk][wn + 7] = w1.w;
        __syncthreads();
#pragma unroll
        for (int kk = 0; kk < 32; kk++) {
            float4 a = *(const float4*)&As[kk][ty * 4];
            float4 b = *(const float4*)&Bs[kk][tx * 4];
            acc[0][0] += a.x * b.x; acc[0][1] += a.x * b.y; acc[0][2] += a.x * b.z; acc[0][3] += a.x * b.w;
            acc[1][0] += a.y * b.x; acc[1][1] += a.y * b.y; acc[1][2] += a.y * b.z; acc[1][3] += a.y * b.w;
            acc[2][0] += a.z * b.x; acc[2][1] += a.z * b.y; acc[2][2] += a.z * b.z; acc[2][3] += a.z * b.w;
            acc[3][0] += a.w * b.x; acc[3][1] += a.w * b.y; acc[3][2] += a.w * b.z; acc[3][3] += a.w * b.w;
        }
        __syncthreads();
    }
#pragma unroll
    for (int i = 0; i < 4; i++) {
        int r = row0 + ty * 4 + i;
        if (r < NN) {
            float4 v = make_float4(acc[i][0], acc[i][1], acc[i][2], acc[i][3]);
            *(float4*)(hfeat + (size_t)r * HD_ + col0 + tx * 4) = v;
        }
    }
}

// ---------------- attention scores a_s, a_d ----------------
// one wave per node; lane -> (head = lane>>4, 4 dims)
__global__ __launch_bounds__(256) void attn_scores(const float* __restrict__ hfeat,
                                                   const float* __restrict__ phi,
                                                   float* __restrict__ a_s,
                                                   float* __restrict__ a_d) {
    int wv = threadIdx.x >> 6, lane = threadIdx.x & 63;
    int n = blockIdx.x * 4 + wv;
    if (n >= NN) return;
    int h = lane >> 4;
    int d0 = (lane & 15) * 4;
    float4 hv = *(const float4*)(hfeat + (size_t)n * HD_ + h * DH_ + d0);
    float ss = 0.f, sd = 0.f;
#pragma unroll
    for (int i = 0; i < 4; i++) {
        float hvv = (i == 0) ? hv.x : (i == 1) ? hv.y : (i == 2) ? hv.z : hv.w;
        float ps = phi[h * 128 + d0 + i];
        float pd = phi[h * 128 + 64 + d0 + i];
        ss += hvv * ps;
        sd += hvv * pd;
    }
#pragma unroll
    for (int o = 1; o < 16; o <<= 1) {
        ss += __shfl_xor(ss, o);
        sd += __shfl_xor(sd, o);
    }
    if ((lane & 15) == 0) {
        a_s[n * 4 + h] = ss;
        a_d[n * 4 + h] = sd;
    }
}

// ---------------- CSR build ----------------
__global__ void hist_deg(const int* __restrict__ src, int* __restrict__ deg) {
    int e = blockIdx.x * 256 + threadIdx.x;
    if (e < EE) atomicAdd(&deg[src[e]], 1);
}

__global__ __launch_bounds__(1024) void scan_off(const int* __restrict__ deg, int* __restrict__ offs) {
    __shared__ int wsum[16];
    int t = threadIdx.x, lane = t & 63, w = t >> 6;
    int running = 0;
    for (int base = 0; base < NN; base += 1024) {
        int i = base + t;
        int v = (i < NN) ? deg[i] : 0;
        int incl = v;
#pragma unroll
        for (int o = 1; o < 64; o <<= 1) {
            int u = __shfl_up(incl, o);
            if (lane >= o) incl += u;
        }
        if (lane == 63) wsum[w] = incl;
        __syncthreads();
        int woff = 0, total = 0;
#pragma unroll
        for (int j = 0; j < 16; j++) {
            int s = wsum[j];
            if (j < w) woff += s;
            total += s;
        }
        if (i < NN) offs[i] = running + woff + incl - v;
        running += total;
        __syncthreads();
    }
    if (t == 0) offs[NN] = running;
}

__global__ void fill_eidx(const int* __restrict__ src, const int* __restrict__ offs,
                          int* __restrict__ cursor, int* __restrict__ eidx) {
    int e = blockIdx.x * 256 + threadIdx.x;
    if (e < EE) {
        int s = src[e];
        int p = offs[s] + atomicAdd(&cursor[s], 1);
        eidx[p] = e;
    }
}

// ---------------- per-node: aggregate + MLP + softmax + group accum ----------------
// one wave (64 lanes) per node, 4 nodes per block
__global__ __launch_bounds__(256) void node_kernel(const float* __restrict__ hfeat,
                                                   const float* __restrict__ a_s,
                                                   const float* __restrict__ a_d,
                                                   const int* __restrict__ offs,
                                                   const int* __restrict__ eidx,
                                                   const int* __restrict__ dstA,
                                                   const int* __restrict__ batch,
                                                   const float* __restrict__ W1,
                                                   const float* __restrict__ b1,
                                                   const float* __restrict__ W2,
                                                   const float* __restrict__ b2,
                                                   float* __restrict__ gsum,
                                                   float* __restrict__ gcnt,
                                                   float* __restrict__ out) {
    __shared__ float aggLds[4][256];
    __shared__ float z1Lds[4][64];
    int wv = threadIdx.x >> 6, lane = threadIdx.x & 63;
    int n = blockIdx.x * 4 + wv;   // grid 12500 * 4 == 50000 exactly

    float4 as4 = *(const float4*)(a_s + (size_t)n * 4);
    int e0 = offs[n], e1 = offs[n + 1];
    float acc0 = 0.f, acc1 = 0.f, acc2 = 0.f, acc3 = 0.f;
    for (int i = e0; i < e1; i++) {
        int e = eidx[i];
        int d = dstA[e];
        float4 ad4 = *(const float4*)(a_d + (size_t)d * 4);
        float w0 = sigm(leaky(as4.x + ad4.x));
        float w1 = sigm(leaky(as4.y + ad4.y));
        float w2 = sigm(leaky(as4.z + ad4.z));
        float w3 = sigm(leaky(as4.w + ad4.w));
        const float* hp = hfeat + (size_t)d * HD_ + lane;
        acc0 += hp[0]   * w0;
        acc1 += hp[64]  * w1;
        acc2 += hp[128] * w2;
        acc3 += hp[192] * w3;
    }
    aggLds[wv][lane]       = acc0;
    aggLds[wv][lane + 64]  = acc1;
    aggLds[wv][lane + 128] = acc2;
    aggLds[wv][lane + 192] = acc3;
    __syncthreads();

    // z1[lane] = leaky(b1 + sum_k agg[k]*W1[k,lane])
    const float* agg = aggLds[wv];
    float s0 = 0.f, s1 = 0.f, s2 = 0.f, s3 = 0.f;
    for (int k = 0; k < 256; k += 4) {
        s0 += agg[k + 0] * W1[(k + 0) * 64 + lane];
        s1 += agg[k + 1] * W1[(k + 1) * 64 + lane];
        s2 += agg[k + 2] * W1[(k + 2) * 64 + lane];
        s3 += agg[k + 3] * W1[(k + 3) * 64 + lane];
    }
    float z1 = leaky(b1[lane] + ((s0 + s1) + (s2 + s3)));
    z1Lds[wv][lane] = z1;
    __syncthreads();

    // z[c] for lanes 0..9
    float z = 0.f;
    if (lane < NC_) {
        z = b2[lane];
#pragma unroll
        for (int k = 0; k < 64; k++) z += z1Lds[wv][k] * W2[k * NC_ + lane];
    }
    // softmax over 10 within the group of 16 lanes
    float zv = (lane < NC_) ? z : -3.0e38f;
    float m = zv;
#pragma unroll
    for (int o = 1; o < 16; o <<= 1) m = fmaxf(m, __shfl_xor(m, o));
    float t = (lane < NC_) ? (__expf(z - m) + EPS_) : 0.f;
    float ssum = t;
#pragma unroll
    for (int o = 1; o < 16; o <<= 1) ssum += __shfl_xor(ssum, o);
    float pred = (lane < NC_) ? (t / ssum) : 0.f;

    if (lane < NC_) {
        out[1000 + (size_t)n * NC_ + lane] = pred;
        int g = batch[n];
        atomicAdd(&gsum[g * NC_ + lane], pred);
        if (lane == 0) atomicAdd(&gcnt[g], 1.0f);
    }
}

// ---------------- finalize log(yp) ----------------
__global__ void finalize(const float* __restrict__ gsum, const float* __restrict__ gcnt,
                         float* __restrict__ out) {
    int i = blockIdx.x * 256 + threadIdx.x;
    if (i < NG_ * NC_) {
        int g = i / NC_;
        out[i] = __logf(gsum[i] / gcnt[g]);
    }
}

extern "C" void kernel_launch(void* const* d_in, const int* in_sizes, int n_in,
                              void* d_out, int out_size, void* d_ws, size_t ws_size,
                              hipStream_t stream) {
    const float* x      = (const float*)d_in[0];
    const int*   midx   = (const int*)d_in[1];
    const int*   batch  = (const int*)d_in[2];
    const float* W_feat = (const float*)d_in[3];
    const float* phi    = (const float*)d_in[4];
    const float* W1     = (const float*)d_in[5];
    const float* b1     = (const float*)d_in[6];
    const float* W2     = (const float*)d_in[7];
    const float* b2     = (const float*)d_in[8];
    const int* src = midx;
    const int* dst = midx + EE;
    float* out = (float*)d_out;

    char* p = (char*)d_ws;
    auto alloc = [&](size_t bytes) { void* r = (void*)p; p += (bytes + 255) & ~(size_t)255; return r; };
    float* hfeat  = (float*)alloc((size_t)NN * HD_ * 4);
    float* a_s    = (float*)alloc((size_t)NN * 4 * 4);
    float* a_d    = (float*)alloc((size_t)NN * 4 * 4);
    int*   deg    = (int*)alloc((size_t)NN * 4);
    int*   offs   = (int*)alloc((size_t)(NN + 1) * 4);
    int*   cursor = (int*)alloc((size_t)NN * 4);
    int*   eidx   = (int*)alloc((size_t)EE * 4);
    float* gsum   = (float*)alloc((size_t)NG_ * NC_ * 4);
    float* gcnt   = (float*)alloc((size_t)NG_ * 4);

    init_zero<<<(NN + 255) / 256, 256, 0, stream>>>(deg, cursor, gsum, gcnt);
    gemm_h<<<dim3((NN + 63) / 64, HD_ / 64), 256, 0, stream>>>(x, W_feat, hfeat);
    attn_scores<<<(NN + 3) / 4, 256, 0, stream>>>(hfeat, phi, a_s, a_d);
    hist_deg<<<(EE + 255) / 256, 256, 0, stream>>>(src, deg);
    scan_off<<<1, 1024, 0, stream>>>(deg, offs);
    fill_eidx<<<(EE + 255) / 256, 256, 0, stream>>>(src, offs, cursor, eidx);
    node_kernel<<<NN / 4, 256, 0, stream>>>(hfeat, a_s, a_d, offs, eidx, dst, batch,
                                            W1, b1, W2, b2, gsum, gcnt, out);
    finalize<<<4, 256, 0, stream>>>(gsum, gcnt, out);
}